// Round 3
// baseline (39.043 us; speedup 1.0000x reference)
//
#include <hip/hip_runtime.h>
#include <math.h>

#define BB 4
#define SS 4096
#define HH 2048
#define DD 3
#define KK 1365            // max(1, int(4096/3))
#define ONEBITS 0x3f800000u
#define TPW 4              // tokens per wave
#define NWAVE 4            // waves per block
#define SBLOCKS (BB * SS / (TPW * NWAVE * 64 / 64) / NWAVE)  // see launch: 1024

// ---------------- Kernel A: scores + loss partials + m0 ones ----------------
// 1024 blocks x 256 threads. Theta staged in LDS once per block (kills the
// 393 MB of theta cache re-reads that thrashed L1/L2 under the hs stream).
// Each wave computes 4 tokens. f64 accumulation, bit-identical order to the
// verified kernel (same v = j*64+lane stride, same x,y,z,w order, same
// shfl-down tree) -> selection-exact.
__global__ __launch_bounds__(256) void score_kernel(
    const float* __restrict__ hs, const float* __restrict__ theta,
    float* __restrict__ scores0, double* __restrict__ partials,
    float* __restrict__ m0)
{
    __shared__ __align__(16) float th[DD * HH];   // 24 KB
    __shared__ double wpart[NWAVE][DD];

    const int tid = threadIdx.x;

    // stage theta -> LDS (1536 float4s, 6 per thread)
    {
        const float4* src = reinterpret_cast<const float4*>(theta);
        float4* dst = reinterpret_cast<float4*>(th);
#pragma unroll
        for (int i = 0; i < 6; ++i) dst[tid + 256 * i] = src[tid + 256 * i];
    }

    // masks[0] is all-ones, data-independent: spread the 64 KB write here.
    const long gid = (long)blockIdx.x * 256 + tid;
    if (gid < (long)BB * SS) m0[gid] = 1.0f;

    __syncthreads();

    const int wave = tid >> 6;
    const int lane = tid & 63;
    const int w    = blockIdx.x * NWAVE + wave;   // global wave id, 0..4095
    const long tok0 = (long)w * TPW;

    const float4* r0 = reinterpret_cast<const float4*>(hs + (tok0 + 0) * HH);
    const float4* r1 = reinterpret_cast<const float4*>(hs + (tok0 + 1) * HH);
    const float4* r2 = reinterpret_cast<const float4*>(hs + (tok0 + 2) * HH);
    const float4* r3 = reinterpret_cast<const float4*>(hs + (tok0 + 3) * HH);
    const float4* t0p = reinterpret_cast<const float4*>(th);
    const float4* t1p = reinterpret_cast<const float4*>(th + HH);
    const float4* t2p = reinterpret_cast<const float4*>(th + 2 * HH);

    double acc[TPW][DD] = {};
#pragma unroll
    for (int j = 0; j < HH / 256; ++j) {   // 8 iters
        const int v = j * 64 + lane;
        const float4 x0 = t0p[v];
        const float4 x1 = t1p[v];
        const float4 x2 = t2p[v];
        const float4 h0 = r0[v];
        const float4 h1 = r1[v];
        const float4 h2 = r2[v];
        const float4 h3 = r3[v];
#define ACCUM(t, h)                                                                           \
        acc[t][0] += (double)h.x * x0.x + (double)h.y * x0.y + (double)h.z * x0.z + (double)h.w * x0.w; \
        acc[t][1] += (double)h.x * x1.x + (double)h.y * x1.y + (double)h.z * x1.z + (double)h.w * x1.w; \
        acc[t][2] += (double)h.x * x2.x + (double)h.y * x2.y + (double)h.z * x2.z + (double)h.w * x2.w;
        ACCUM(0, h0) ACCUM(1, h1) ACCUM(2, h2) ACCUM(3, h3)
#undef ACCUM
    }

#pragma unroll
    for (int t = 0; t < TPW; ++t)
#pragma unroll
        for (int d = 0; d < DD; ++d)
#pragma unroll
            for (int off = 32; off; off >>= 1)
                acc[t][d] += __shfl_down(acc[t][d], off);

    if (lane == 0) {
        double ss0 = 0.0, ss1 = 0.0, ss2 = 0.0;
#pragma unroll
        for (int t = 0; t < TPW; ++t) {
            const float x0 = (float)acc[t][0];
            const float x1 = (float)acc[t][1];
            const float x2 = (float)acc[t][2];
            const float s0 = 1.0f / (1.0f + expf(-x0));
            const float s1 = 1.0f / (1.0f + expf(-x1));
            const float s2 = 1.0f / (1.0f + expf(-x2));
            scores0[tok0 + t] = s0;
            ss0 += (double)(1.0f / (1.0f + expf(-s0)));
            ss1 += (double)(1.0f / (1.0f + expf(-s1)));
            ss2 += (double)(1.0f / (1.0f + expf(-s2)));
        }
        wpart[wave][0] = ss0; wpart[wave][1] = ss1; wpart[wave][2] = ss2;
    }
    __syncthreads();
    if (tid < DD) {
        const int d = tid;
        partials[(long)blockIdx.x * DD + d] =
            wpart[0][d] + wpart[1][d] + wpart[2][d] + wpart[3][d];
    }
}

// ---------------- Kernel B: selection (12 blocks) + loss (block 12) ---------
// Blocks 0..11: (row b = blk/3, plane = blk%3 of {depth, m1, m2}).
// Fast path: sigmoid <= 1.0f, so if count(score==1.0f) >= k the k-th largest
// is exactly 1.0f and selection = first k indices equal to 1.0f (one scan).
// Fallback: exact 4x8-bit radix select (verified round 1), block-uniform.
__global__ __launch_bounds__(1024) void select_kernel(
    const float* __restrict__ scores0, const double* __restrict__ partials,
    float* __restrict__ out)
{
    const int tid  = threadIdx.x;
    const int lane = tid & 63;
    const int wid  = tid >> 6;
    const int blk  = blockIdx.x;

    if (blk == 12) {   // ---- balancing loss ----
        double a0 = 0.0, a1 = 0.0, a2 = 0.0;
        for (int i = tid; i < 1024; i += 1024) {
            a0 += partials[(long)i * DD + 0];
            a1 += partials[(long)i * DD + 1];
            a2 += partials[(long)i * DD + 2];
        }
#pragma unroll
        for (int off = 32; off; off >>= 1) {
            a0 += __shfl_down(a0, off);
            a1 += __shfl_down(a1, off);
            a2 += __shfl_down(a2, off);
        }
        __shared__ double shl[DD][16];
        if (lane == 0) { shl[0][wid] = a0; shl[1][wid] = a1; shl[2][wid] = a2; }
        __syncthreads();
        if (tid == 0) {
            double p0 = 0, p1 = 0, p2 = 0;
            for (int w = 0; w < 16; ++w) { p0 += shl[0][w]; p1 += shl[1][w]; p2 += shl[2][w]; }
            const double n = (double)BB * SS;
            p0 /= n; p1 /= n; p2 /= n;
            const double t = 1.0 / 3.0;
            out[(long)BB * SS] = (float)((t * (log(t) - log(p0)) +
                                          t * (log(t) - log(p1)) +
                                          t * (log(t) - log(p2))) / 3.0);
        }
        return;
    }

    const int b = blk / 3, plane = blk % 3;
    const float* rowp = scores0 + (long)b * SS;

    __shared__ unsigned wsum[16];
    __shared__ __align__(16) unsigned su[SS];   // fallback only
    __shared__ unsigned whist[16 * 256];        // fallback only
    __shared__ unsigned wtot[4];
    __shared__ unsigned sbin, skk;

    uint4 uu = reinterpret_cast<const uint4*>(rowp)[tid];

    unsigned vstar = ONEBITS;
    unsigned e0 = (uu.x == vstar), e1 = (uu.y == vstar),
             e2 = (uu.z == vstar), e3 = (uu.w == vstar);
    unsigned cnt = e0 + e1 + e2 + e3;

    // block exclusive scan of cnt (also yields block total)
    unsigned inc = cnt;
#pragma unroll
    for (int off = 1; off < 64; off <<= 1) {
        unsigned t = __shfl_up(inc, off);
        if (lane >= off) inc += t;
    }
    if (lane == 63) wsum[wid] = inc;
    __syncthreads();
    if (wid == 0) {
        unsigned wv = (lane < 16) ? wsum[lane] : 0;
#pragma unroll
        for (int off = 1; off < 16; off <<= 1) {
            unsigned t = __shfl_up(wv, off);
            if (lane >= off) wv += t;
        }
        if (lane < 16) wsum[lane] = wv;
    }
    __syncthreads();
    unsigned p     = inc - cnt + (wid > 0 ? wsum[wid - 1] : 0);
    unsigned total = wsum[15];
    unsigned rem   = KK;

    if (total < KK) {   // ---- block-uniform fallback: exact radix select ----
        for (int i = tid; i < SS; i += 1024) su[i] = __float_as_uint(rowp[i]);
        unsigned prefix = 0, maskbits = 0, kk = KK;
        for (int pass = 0; pass < 4; ++pass) {
            const int shift = 24 - 8 * pass;
            for (int i = tid; i < 16 * 256; i += 1024) whist[i] = 0;
            __syncthreads();
            for (int i = tid; i < SS; i += 1024) {
                unsigned u = su[i];
                if ((u & maskbits) == prefix)
                    atomicAdd(&whist[(wid << 8) + ((u >> shift) & 255u)], 1u);
            }
            __syncthreads();
            unsigned val = 0, s = 0;
            if (tid < 256) {
                for (int w = 0; w < 16; ++w) val += whist[(w << 8) + tid];
                s = val;
#pragma unroll
                for (int off = 1; off < 64; off <<= 1) {
                    unsigned t = __shfl_down(s, off);
                    if (lane + off < 64) s += t;
                }
                if (lane == 0) wtot[wid] = s;
            }
            __syncthreads();
            if (tid < 256) {
                unsigned cge = s;
                for (int w = wid + 1; w < 4; ++w) cge += wtot[w];
                unsigned cgt = cge - val;
                if (cgt < kk && cge >= kk) { sbin = (unsigned)tid; skk = kk - cgt; }
            }
            __syncthreads();
            prefix   |= (sbin << shift);
            maskbits |= (255u << shift);
            kk = skk;
        }
        vstar = prefix;
        rem   = kk;
        // recompute equality flags and redo the scan for the new vstar
        e0 = (uu.x == vstar); e1 = (uu.y == vstar);
        e2 = (uu.z == vstar); e3 = (uu.w == vstar);
        cnt = e0 + e1 + e2 + e3;
        inc = cnt;
#pragma unroll
        for (int off = 1; off < 64; off <<= 1) {
            unsigned t = __shfl_up(inc, off);
            if (lane >= off) inc += t;
        }
        __syncthreads();   // protect wsum reuse
        if (lane == 63) wsum[wid] = inc;
        __syncthreads();
        if (wid == 0) {
            unsigned wv = (lane < 16) ? wsum[lane] : 0;
#pragma unroll
            for (int off = 1; off < 16; off <<= 1) {
                unsigned t = __shfl_up(wv, off);
                if (lane >= off) wv += t;
            }
            if (lane < 16) wsum[lane] = wv;
        }
        __syncthreads();
        p = inc - cnt + (wid > 0 ? wsum[wid - 1] : 0);
    }

    // selection: strictly-greater always in; ties by lowest index
    const bool sel0 = (uu.x > vstar) || (e0 && p < rem); p += e0;
    const bool sel1 = (uu.y > vstar) || (e1 && p < rem); p += e1;
    const bool sel2 = (uu.z > vstar) || (e2 && p < rem); p += e2;
    const bool sel3 = (uu.w > vstar) || (e3 && p < rem);

    if (plane == 0) {
        float4 dv = make_float4(sel0 ? 3.0f : 1.0f, sel1 ? 3.0f : 1.0f,
                                sel2 ? 3.0f : 1.0f, sel3 ? 3.0f : 1.0f);
        reinterpret_cast<float4*>(out + (long)b * SS)[tid] = dv;
    } else {
        // masks base is out + B*S + 1 (odd float offset -> scalar stores)
        float* m = out + (long)BB * SS + 1 + (long)plane * BB * SS + (long)b * SS;
        const int base = tid * 4;
        m[base + 0] = sel0 ? 1.0f : 0.0f;
        m[base + 1] = sel1 ? 1.0f : 0.0f;
        m[base + 2] = sel2 ? 1.0f : 0.0f;
        m[base + 3] = sel3 ? 1.0f : 0.0f;
    }
}

extern "C" void kernel_launch(void* const* d_in, const int* in_sizes, int n_in,
                              void* d_out, int out_size, void* d_ws, size_t ws_size,
                              hipStream_t stream) {
    const float* hs    = (const float*)d_in[0];
    const float* theta = (const float*)d_in[1];
    float* out = (float*)d_out;

    float*  scores0  = (float*)d_ws;                                  // 64 KB
    double* partials = (double*)((char*)d_ws + (size_t)BB * SS * 4);  // 24 KB
    float*  m0       = out + (long)BB * SS + 1;                       // masks[0]

    score_kernel <<<dim3(1024), dim3(256),  0, stream>>>(hs, theta, scores0, partials, m0);
    select_kernel<<<dim3(13),   dim3(1024), 0, stream>>>(scores0, partials, out);
}

// Round 4
// 37.190 us; speedup vs baseline: 1.0498x; 1.0498x over previous
//
#include <hip/hip_runtime.h>
#include <math.h>

#define BB 4
#define SS 4096
#define HH 2048
#define DD 3
#define KK 1365            // max(1, int(4096/3))
#define ONEBITS 0x3f800000u
#define NW 8               // waves per block (512 threads)
#define NBLK (BB * SS / NW)   // 2048 blocks, 1 token per wave

// ---------------- Kernel A: scores + loss partials + m0 ones ----------------
// 2048 blocks x 512 threads (8 waves). Theta staged once per block in LDS
// (24 KB -> 4 blocks/CU = 32 waves/CU, FULL occupancy — R3's mistake was
// 16 waves/CU). One token per wave; accumulation order bit-identical to the
// verified R2 kernel (v = j*64+lane, x,y,z,w order, same shfl-down tree).
__global__ __launch_bounds__(512, 8) void score_kernel(
    const float* __restrict__ hs, const float* __restrict__ theta,
    float* __restrict__ scores0, double* __restrict__ partials,
    float* __restrict__ m0)
{
    __shared__ __align__(16) float th[DD * HH];   // 24 KB
    __shared__ double wpart[NW][DD];

    const int tid = threadIdx.x;

    // stage theta -> LDS (1536 float4s, 3 per thread), coalesced
    {
        const float4* src = reinterpret_cast<const float4*>(theta);
        float4* dst = reinterpret_cast<float4*>(th);
#pragma unroll
        for (int i = 0; i < 3; ++i) dst[tid + 512 * i] = src[tid + 512 * i];
    }

    // masks[0] is all-ones, data-independent: spread the 64 KB write here.
    const long gid = (long)blockIdx.x * 512 + tid;
    if (gid < (long)BB * SS) m0[gid] = 1.0f;

    __syncthreads();

    const int wave = tid >> 6;
    const int lane = tid & 63;
    const long token = (long)blockIdx.x * NW + wave;   // 0..16383

    const float4* row = reinterpret_cast<const float4*>(hs + token * HH);
    const float4* t0p = reinterpret_cast<const float4*>(th);
    const float4* t1p = reinterpret_cast<const float4*>(th + HH);
    const float4* t2p = reinterpret_cast<const float4*>(th + 2 * HH);

    double a0 = 0.0, a1 = 0.0, a2 = 0.0;
#pragma unroll
    for (int j = 0; j < HH / 256; ++j) {   // 8 iters
        const int v = j * 64 + lane;
        const float4 h  = row[v];
        const float4 x0 = t0p[v];
        const float4 x1 = t1p[v];
        const float4 x2 = t2p[v];
        a0 += (double)h.x * x0.x + (double)h.y * x0.y + (double)h.z * x0.z + (double)h.w * x0.w;
        a1 += (double)h.x * x1.x + (double)h.y * x1.y + (double)h.z * x1.z + (double)h.w * x1.w;
        a2 += (double)h.x * x2.x + (double)h.y * x2.y + (double)h.z * x2.z + (double)h.w * x2.w;
    }
#pragma unroll
    for (int off = 32; off; off >>= 1) {
        a0 += __shfl_down(a0, off);
        a1 += __shfl_down(a1, off);
        a2 += __shfl_down(a2, off);
    }

    if (lane == 0) {
        const float x0 = (float)a0, x1 = (float)a1, x2 = (float)a2;
        const float s0 = 1.0f / (1.0f + expf(-x0));
        const float s1 = 1.0f / (1.0f + expf(-x1));
        const float s2 = 1.0f / (1.0f + expf(-x2));
        scores0[token] = s0;
        wpart[wave][0] = (double)(1.0f / (1.0f + expf(-s0)));
        wpart[wave][1] = (double)(1.0f / (1.0f + expf(-s1)));
        wpart[wave][2] = (double)(1.0f / (1.0f + expf(-s2)));
    }
    __syncthreads();
    if (tid < DD) {
        const int d = tid;
        double s = 0.0;
#pragma unroll
        for (int w = 0; w < NW; ++w) s += wpart[w][d];
        partials[(long)blockIdx.x * DD + d] = s;
    }
}

// ---------------- Kernel B: selection (12 blocks) + loss (block 12) ---------
// Blocks 0..11: (row b = blk/3, plane = blk%3 of {depth, m1, m2}).
// Fast path: sigmoid <= 1.0f, so if count(score==1.0f) >= k the k-th largest
// is exactly 1.0f and selection = first k indices equal to 1.0f (one scan).
// Fallback: exact 4x8-bit radix select (verified round 1), block-uniform.
__global__ __launch_bounds__(1024) void select_kernel(
    const float* __restrict__ scores0, const double* __restrict__ partials,
    float* __restrict__ out)
{
    const int tid  = threadIdx.x;
    const int lane = tid & 63;
    const int wid  = tid >> 6;
    const int blk  = blockIdx.x;

    if (blk == 12) {   // ---- balancing loss ----
        double a0 = 0.0, a1 = 0.0, a2 = 0.0;
        for (int i = tid; i < NBLK; i += 1024) {
            a0 += partials[(long)i * DD + 0];
            a1 += partials[(long)i * DD + 1];
            a2 += partials[(long)i * DD + 2];
        }
#pragma unroll
        for (int off = 32; off; off >>= 1) {
            a0 += __shfl_down(a0, off);
            a1 += __shfl_down(a1, off);
            a2 += __shfl_down(a2, off);
        }
        __shared__ double shl[DD][16];
        if (lane == 0) { shl[0][wid] = a0; shl[1][wid] = a1; shl[2][wid] = a2; }
        __syncthreads();
        if (tid == 0) {
            double p0 = 0, p1 = 0, p2 = 0;
            for (int w = 0; w < 16; ++w) { p0 += shl[0][w]; p1 += shl[1][w]; p2 += shl[2][w]; }
            const double n = (double)BB * SS;
            p0 /= n; p1 /= n; p2 /= n;
            const double t = 1.0 / 3.0;
            out[(long)BB * SS] = (float)((t * (log(t) - log(p0)) +
                                          t * (log(t) - log(p1)) +
                                          t * (log(t) - log(p2))) / 3.0);
        }
        return;
    }

    const int b = blk / 3, plane = blk % 3;
    const float* rowp = scores0 + (long)b * SS;

    __shared__ unsigned wsum[16];
    __shared__ __align__(16) unsigned su[SS];   // fallback only
    __shared__ unsigned whist[16 * 256];        // fallback only
    __shared__ unsigned wtot[4];
    __shared__ unsigned sbin, skk;

    uint4 uu = reinterpret_cast<const uint4*>(rowp)[tid];

    unsigned vstar = ONEBITS;
    unsigned e0 = (uu.x == vstar), e1 = (uu.y == vstar),
             e2 = (uu.z == vstar), e3 = (uu.w == vstar);
    unsigned cnt = e0 + e1 + e2 + e3;

    // block exclusive scan of cnt (also yields block total)
    unsigned inc = cnt;
#pragma unroll
    for (int off = 1; off < 64; off <<= 1) {
        unsigned t = __shfl_up(inc, off);
        if (lane >= off) inc += t;
    }
    if (lane == 63) wsum[wid] = inc;
    __syncthreads();
    if (wid == 0) {
        unsigned wv = (lane < 16) ? wsum[lane] : 0;
#pragma unroll
        for (int off = 1; off < 16; off <<= 1) {
            unsigned t = __shfl_up(wv, off);
            if (lane >= off) wv += t;
        }
        if (lane < 16) wsum[lane] = wv;
    }
    __syncthreads();
    unsigned p     = inc - cnt + (wid > 0 ? wsum[wid - 1] : 0);
    unsigned total = wsum[15];
    unsigned rem   = KK;

    if (total < KK) {   // ---- block-uniform fallback: exact radix select ----
        for (int i = tid; i < SS; i += 1024) su[i] = __float_as_uint(rowp[i]);
        unsigned prefix = 0, maskbits = 0, kk = KK;
        for (int pass = 0; pass < 4; ++pass) {
            const int shift = 24 - 8 * pass;
            for (int i = tid; i < 16 * 256; i += 1024) whist[i] = 0;
            __syncthreads();
            for (int i = tid; i < SS; i += 1024) {
                unsigned u = su[i];
                if ((u & maskbits) == prefix)
                    atomicAdd(&whist[(wid << 8) + ((u >> shift) & 255u)], 1u);
            }
            __syncthreads();
            unsigned val = 0, s = 0;
            if (tid < 256) {
                for (int w = 0; w < 16; ++w) val += whist[(w << 8) + tid];
                s = val;
#pragma unroll
                for (int off = 1; off < 64; off <<= 1) {
                    unsigned t = __shfl_down(s, off);
                    if (lane + off < 64) s += t;
                }
                if (lane == 0) wtot[wid] = s;
            }
            __syncthreads();
            if (tid < 256) {
                unsigned cge = s;
                for (int w = wid + 1; w < 4; ++w) cge += wtot[w];
                unsigned cgt = cge - val;
                if (cgt < kk && cge >= kk) { sbin = (unsigned)tid; skk = kk - cgt; }
            }
            __syncthreads();
            prefix   |= (sbin << shift);
            maskbits |= (255u << shift);
            kk = skk;
        }
        vstar = prefix;
        rem   = kk;
        // recompute equality flags and redo the scan for the new vstar
        e0 = (uu.x == vstar); e1 = (uu.y == vstar);
        e2 = (uu.z == vstar); e3 = (uu.w == vstar);
        cnt = e0 + e1 + e2 + e3;
        inc = cnt;
#pragma unroll
        for (int off = 1; off < 64; off <<= 1) {
            unsigned t = __shfl_up(inc, off);
            if (lane >= off) inc += t;
        }
        __syncthreads();   // protect wsum reuse
        if (lane == 63) wsum[wid] = inc;
        __syncthreads();
        if (wid == 0) {
            unsigned wv = (lane < 16) ? wsum[lane] : 0;
#pragma unroll
            for (int off = 1; off < 16; off <<= 1) {
                unsigned t = __shfl_up(wv, off);
                if (lane >= off) wv += t;
            }
            if (lane < 16) wsum[lane] = wv;
        }
        __syncthreads();
        p = inc - cnt + (wid > 0 ? wsum[wid - 1] : 0);
    }

    // selection: strictly-greater always in; ties by lowest index
    const bool sel0 = (uu.x > vstar) || (e0 && p < rem); p += e0;
    const bool sel1 = (uu.y > vstar) || (e1 && p < rem); p += e1;
    const bool sel2 = (uu.z > vstar) || (e2 && p < rem); p += e2;
    const bool sel3 = (uu.w > vstar) || (e3 && p < rem);

    if (plane == 0) {
        float4 dv = make_float4(sel0 ? 3.0f : 1.0f, sel1 ? 3.0f : 1.0f,
                                sel2 ? 3.0f : 1.0f, sel3 ? 3.0f : 1.0f);
        reinterpret_cast<float4*>(out + (long)b * SS)[tid] = dv;
    } else {
        // masks base is out + B*S + 1 (odd float offset -> scalar stores)
        float* m = out + (long)BB * SS + 1 + (long)plane * BB * SS + (long)b * SS;
        const int base = tid * 4;
        m[base + 0] = sel0 ? 1.0f : 0.0f;
        m[base + 1] = sel1 ? 1.0f : 0.0f;
        m[base + 2] = sel2 ? 1.0f : 0.0f;
        m[base + 3] = sel3 ? 1.0f : 0.0f;
    }
}

extern "C" void kernel_launch(void* const* d_in, const int* in_sizes, int n_in,
                              void* d_out, int out_size, void* d_ws, size_t ws_size,
                              hipStream_t stream) {
    const float* hs    = (const float*)d_in[0];
    const float* theta = (const float*)d_in[1];
    float* out = (float*)d_out;

    float*  scores0  = (float*)d_ws;                                  // 64 KB
    double* partials = (double*)((char*)d_ws + (size_t)BB * SS * 4);  // 48 KB
    float*  m0       = out + (long)BB * SS + 1;                       // masks[0]

    score_kernel <<<dim3(NBLK), dim3(512),  0, stream>>>(hs, theta, scores0, partials, m0);
    select_kernel<<<dim3(13),   dim3(1024), 0, stream>>>(scores0, partials, out);
}